// Round 8
// baseline (457.961 us; speedup 1.0000x reference)
//
#include <hip/hip_runtime.h>

typedef unsigned short u16;
typedef __attribute__((ext_vector_type(8))) short bf16x8;
typedef __attribute__((ext_vector_type(4))) float f32x4;
typedef __attribute__((ext_vector_type(4))) unsigned short u16x4;

#define MFMA16(a, b, c) __builtin_amdgcn_mfma_f32_16x16x32_bf16((a), (b), (c), 0, 0, 0)

__device__ __forceinline__ u16 f2bf(float f) {
  union { float f; unsigned int i; } v; v.f = f;
  return (u16)((v.i + 0x7FFFu + ((v.i >> 16) & 1u)) >> 16);
}

// ---------------- transpose fp32 -> bf16: dst[C][R] = src[R][C] ----------------
__global__ __launch_bounds__(256) void k_transpose(const float* __restrict__ src,
                                                   u16* __restrict__ dst, int R, int C) {
  __shared__ u16 tile[64][65];
  const int c0 = blockIdx.x * 64, r0 = blockIdx.y * 64;
  const int t = threadIdx.x;
#pragma unroll
  for (int i = 0; i < 16; ++i) {
    int e = i * 256 + t, rr = e >> 6, cc = e & 63;
    tile[rr][cc] = f2bf(src[(size_t)(r0 + rr) * C + c0 + cc]);
  }
  __syncthreads();
#pragma unroll
  for (int i = 0; i < 16; ++i) {
    int e = i * 256 + t, rr = e >> 6, cc = e & 63;
    dst[(size_t)(c0 + rr) * R + r0 + cc] = tile[cc][rr];
  }
}

// ---------------- GEMM: A[M][K] @ Bt[N][K]^T ----------------
// QKV=1: A fp32, epilogue scatters bf16 to Q/K/V^T.
// QKV=0: A bf16, epilogue writes fp32 C + fp32 bias.
template <int QKV>
__global__ __launch_bounds__(256) void k_gemm(
    const void* __restrict__ Ap, const u16* __restrict__ Bt,
    const float* __restrict__ bias, float* __restrict__ Cf,
    u16* __restrict__ Qb, u16* __restrict__ Kb, u16* __restrict__ VTb,
    int M, int N, int K) {
  __shared__ __attribute__((aligned(16))) u16 As[128 * 32];  // [row][k]
  __shared__ __attribute__((aligned(16))) u16 Bs[128 * 32];  // [col][k]
  const int bn = blockIdx.x, bm = blockIdx.y;
  const int t = threadIdx.x, lane = t & 63, w = t >> 6;
  const int wr = w >> 1, wc = w & 1;        // 2x2 wave grid, 64x64 per wave
  const int rh = lane & 15, kg = lane >> 4; // fragment row / k-group

  f32x4 acc[4][4];
#pragma unroll
  for (int mi = 0; mi < 4; ++mi)
#pragma unroll
    for (int ni = 0; ni < 4; ++ni) acc[mi][ni] = (f32x4)0.0f;

  for (int k0 = 0; k0 < K; k0 += 32) {
#pragma unroll
    for (int i = 0; i < 2; ++i) {
      int c = t + 256 * i;
      int r = c >> 2, c8 = (c & 3) << 3;
      // A tile
      if (QKV) {  // fp32 -> bf16
        const float* s = (const float*)Ap + (size_t)(bm * 128 + r) * K + k0 + c8;
        float4 a = *(const float4*)s;
        float4 b4 = *(const float4*)(s + 4);
        union { u16 e[8]; int4 v; } u;
        u.e[0] = f2bf(a.x); u.e[1] = f2bf(a.y); u.e[2] = f2bf(a.z); u.e[3] = f2bf(a.w);
        u.e[4] = f2bf(b4.x); u.e[5] = f2bf(b4.y); u.e[6] = f2bf(b4.z); u.e[7] = f2bf(b4.w);
        *(int4*)(&As[r * 32 + c8]) = u.v;
      } else {    // bf16 copy
        const u16* s = (const u16*)Ap + (size_t)(bm * 128 + r) * K + k0 + c8;
        *(int4*)(&As[r * 32 + c8]) = *(const int4*)s;
      }
      // B tile: bf16 [N][K] -> contiguous 16B copy (conflict-free)
      const u16* sb = Bt + (size_t)(bn * 128 + r) * K + k0 + c8;
      *(int4*)(&Bs[r * 32 + c8]) = *(const int4*)sb;
    }
    __syncthreads();
    bf16x8 af[4], bfr[4];
#pragma unroll
    for (int mi = 0; mi < 4; ++mi)
      af[mi] = *(const bf16x8*)(&As[(wr * 64 + mi * 16 + rh) * 32 + kg * 8]);
#pragma unroll
    for (int ni = 0; ni < 4; ++ni)
      bfr[ni] = *(const bf16x8*)(&Bs[(wc * 64 + ni * 16 + rh) * 32 + kg * 8]);
#pragma unroll
    for (int mi = 0; mi < 4; ++mi)
#pragma unroll
      for (int ni = 0; ni < 4; ++ni)
        acc[mi][ni] = MFMA16(af[mi], bfr[ni], acc[mi][ni]);
    __syncthreads();
  }

  if (QKV == 0) {
    const int rbase = bm * 128 + wr * 64;
    const int cbase = bn * 128 + wc * 64;
#pragma unroll
    for (int ni = 0; ni < 4; ++ni) {
      const int col = cbase + ni * 16 + rh;
      const float bv = bias ? bias[col] : 0.0f;
#pragma unroll
      for (int mi = 0; mi < 4; ++mi) {
#pragma unroll
        for (int r = 0; r < 4; ++r) {
          int row = rbase + mi * 16 + kg * 4 + r;
          Cf[(size_t)row * N + col] = acc[mi][ni][r] + bv;
        }
      }
    }
  } else {
    // qkv scatter: row = b*2048+t, col in [0,3072): role=col/1024, h=(col%1024)/64, d=col%64
    const int rowbase = bm * 128 + wr * 64;
    const int b = rowbase >> 11;
    const int tb = rowbase & 2047;
    const int cbase = bn * 128 + wc * 64;  // 64-aligned -> role/h uniform per wave
    const int role = cbase >> 10;
    const int h = (cbase & 1023) >> 6;
    const int bh = b * 16 + h;
#pragma unroll
    for (int ni = 0; ni < 4; ++ni) {
      const int d = ni * 16 + rh;
#pragma unroll
      for (int mi = 0; mi < 4; ++mi) {
        const int tt = tb + mi * 16 + kg * 4;
        if (role == 2) {
          u16x4 pk;
#pragma unroll
          for (int r = 0; r < 4; ++r) pk[r] = f2bf(acc[mi][ni][r]);
          *(u16x4*)(&VTb[((size_t)bh * 64 + d) * 2048 + tt]) = pk;  // V^T[bh][d][t]
        } else {
          u16* dst = (role == 0) ? Qb : Kb;
#pragma unroll
          for (int r = 0; r < 4; ++r)
            dst[((size_t)bh * 2048 + tt + r) * 64 + d] = f2bf(acc[mi][ni][r]);
        }
      }
    }
  }
}

// ---------------- causal flash attention: 4-wave blocks, LDS K/V, XOR swizzle ----------------
// Q,K: [BH][2048][64]; VT: [BH][64][2048]; Y: [B*2048][1024] bf16
// Grid (64 bh, 16 qb'), 256 threads. Block owns q-rows [qB, qB+128) with qb = 15-y (LPT).
// Wave w owns rows {qB + l*4 + w, l=0..31} (mod-4 interleave -> all waves share the same
// causal range -> perfect intra-block balance). K/V tiles (64x64) staged in LDS per tile,
// all addresses XOR-swizzled by ((row&7)<<4) on write AND read (T2, both-sides).
__global__ __launch_bounds__(256, 4) void k_attn(const u16* __restrict__ Qb,
                                                 const u16* __restrict__ Kb,
                                                 const u16* __restrict__ VTb,
                                                 u16* __restrict__ Y) {
  __shared__ __attribute__((aligned(16))) char Ks[64 * 128];      // K tile, swizzled
  __shared__ __attribute__((aligned(16))) char Vs[64 * 128];      // V^T tile, swizzled
  __shared__ __attribute__((aligned(16))) char Pw[4][32 * 128];   // per-wave P, swizzled
  const int bh = blockIdx.x;
  const int qb = 15 - (int)blockIdx.y;  // LPT: big q-tiles first
  const int t = threadIdx.x, lane = t & 63, w = t >> 6;
  const int rh = lane & 15, kg = lane >> 4;
  const int qB = qb * 128;
  const u16* Qh = Qb + (size_t)bh * 2048 * 64;
  const u16* Kh = Kb + (size_t)bh * 2048 * 64;
  const u16* Vh = VTb + (size_t)bh * 64 * 2048;
  const int b = bh >> 4, h = bh & 15;
  const float SC = 0.125f * 1.44269504f;  // qk-scale * log2(e): exp2 domain

  // Q fragments: wave's A-frag row rh of block rb = global q-row qB + (rb*16+rh)*4 + w
  bf16x8 qf[2][2];
#pragma unroll
  for (int rb = 0; rb < 2; ++rb) {
    const int qrow = qB + (rb * 16 + rh) * 4 + w;
    qf[rb][0] = *(const bf16x8*)(&Qh[(size_t)qrow * 64 + kg * 8]);
    qf[rb][1] = *(const bf16x8*)(&Qh[(size_t)qrow * 64 + 32 + kg * 8]);
  }

  float m[2][4], s[2][4];
  f32x4 yacc[2][4];
#pragma unroll
  for (int rb = 0; rb < 2; ++rb) {
#pragma unroll
    for (int r = 0; r < 4; ++r) { m[rb][r] = -1e30f; s[rb][r] = 0.0f; }
#pragma unroll
    for (int dt = 0; dt < 4; ++dt) yacc[rb][dt] = (f32x4)0.0f;
  }

  const int nt = 2 * qb + 2;  // 64-col k-tiles covering cols <= qB+127
  for (int tt = 0; tt < nt; ++tt) {
    const int j0 = tt * 64;
    // ---- cooperative K/V staging (swizzled dest; 16B lanes, conflict-free) ----
#pragma unroll
    for (int i = 0; i < 2; ++i) {
      const int c = i * 256 + t;             // 0..511
      const int row = c >> 3, cb = (c & 7) << 4;
      const int dst = row * 128 + (cb ^ ((row & 7) << 4));
      *(int4*)(Ks + dst) = *(const int4*)(&Kh[(size_t)(j0 + row) * 64 + (cb >> 1)]);
      *(int4*)(Vs + dst) = *(const int4*)(&Vh[(size_t)row * 2048 + j0 + (cb >> 1)]);
    }
    __syncthreads();

    // ---- QK^T for 64 k-cols ----
    f32x4 sa[2][4];
    __builtin_amdgcn_s_setprio(1);
#pragma unroll
    for (int kk = 0; kk < 4; ++kk) {
      const int krow = kk * 16 + rh;
      const int sx = (krow & 7) << 4;
      const bf16x8 kfa = *(const bf16x8*)(Ks + krow * 128 + ((kg * 16) ^ sx));
      const bf16x8 kfb = *(const bf16x8*)(Ks + krow * 128 + ((64 + kg * 16) ^ sx));
#pragma unroll
      for (int rb = 0; rb < 2; ++rb) {
        sa[rb][kk] = MFMA16(qf[rb][0], kfa, (f32x4)0.0f);
        sa[rb][kk] = MFMA16(qf[rb][1], kfb, sa[rb][kk]);
      }
    }
    __builtin_amdgcn_s_setprio(0);

    // ---- online softmax over 64 cols ----
    const bool need_mask = (j0 + 64 > qB);  // wave-uniform: only last two tiles
    char* const pw = Pw[w];
#pragma unroll
    for (int rb = 0; rb < 2; ++rb) {
      float scf[4];
#pragma unroll
      for (int r = 0; r < 4; ++r) {
        const int l = rb * 16 + kg * 4 + r;        // local P row
        const int qrow = qB + l * 4 + w;
        float v[4];
#pragma unroll
        for (int kk = 0; kk < 4; ++kk) v[kk] = sa[rb][kk][r] * SC;
        if (need_mask) {
#pragma unroll
          for (int kk = 0; kk < 4; ++kk)
            if (j0 + kk * 16 + rh > qrow) v[kk] = -1e30f;
        }
        float mx = fmaxf(fmaxf(v[0], v[1]), fmaxf(v[2], v[3]));
        mx = fmaxf(mx, __shfl_xor(mx, 1));
        mx = fmaxf(mx, __shfl_xor(mx, 2));
        mx = fmaxf(mx, __shfl_xor(mx, 4));
        mx = fmaxf(mx, __shfl_xor(mx, 8));
        const float mn = fmaxf(m[rb][r], mx);
        scf[r] = exp2f(m[rb][r] - mn);
        const float p0 = exp2f(v[0] - mn);
        const float p1 = exp2f(v[1] - mn);
        const float p2 = exp2f(v[2] - mn);
        const float p3 = exp2f(v[3] - mn);
        float rs = (p0 + p1) + (p2 + p3);
        rs += __shfl_xor(rs, 1);
        rs += __shfl_xor(rs, 2);
        rs += __shfl_xor(rs, 4);
        rs += __shfl_xor(rs, 8);
        s[rb][r] = s[rb][r] * scf[r] + rs;
        m[rb][r] = mn;
        const int rbase = l * 128, sx = (l & 7) << 4;
        *(u16*)(pw + rbase + ((rh * 2) ^ sx)) = f2bf(p0);
        *(u16*)(pw + rbase + ((32 + rh * 2) ^ sx)) = f2bf(p1);
        *(u16*)(pw + rbase + ((64 + rh * 2) ^ sx)) = f2bf(p2);
        *(u16*)(pw + rbase + ((96 + rh * 2) ^ sx)) = f2bf(p3);
      }
#pragma unroll
      for (int dt = 0; dt < 4; ++dt)
#pragma unroll
        for (int r = 0; r < 4; ++r) yacc[rb][dt][r] *= scf[r];
    }

    // per-wave LDS fence: P writes -> P fragment reads
    asm volatile("s_waitcnt lgkmcnt(0)" ::: "memory");
    __builtin_amdgcn_sched_barrier(0);
    bf16x8 pf[2][2];
#pragma unroll
    for (int rb = 0; rb < 2; ++rb) {
      const int lr = rb * 16 + rh;
      const int sx = (lr & 7) << 4;
      pf[rb][0] = *(const bf16x8*)(pw + lr * 128 + ((kg * 16) ^ sx));
      pf[rb][1] = *(const bf16x8*)(pw + lr * 128 + ((64 + kg * 16) ^ sx));
    }
    __builtin_amdgcn_s_setprio(1);
#pragma unroll
    for (int dt = 0; dt < 4; ++dt) {
      const int vrow = dt * 16 + rh;
      const int sx = (vrow & 7) << 4;
      const bf16x8 vf0 = *(const bf16x8*)(Vs + vrow * 128 + ((kg * 16) ^ sx));
      const bf16x8 vf1 = *(const bf16x8*)(Vs + vrow * 128 + ((64 + kg * 16) ^ sx));
#pragma unroll
      for (int rb = 0; rb < 2; ++rb) {
        yacc[rb][dt] = MFMA16(pf[rb][0], vf0, yacc[rb][dt]);
        yacc[rb][dt] = MFMA16(pf[rb][1], vf1, yacc[rb][dt]);
      }
    }
    __builtin_amdgcn_s_setprio(0);
    __syncthreads();  // K/V tile consumed; safe to restage
  }

#pragma unroll
  for (int rb = 0; rb < 2; ++rb)
#pragma unroll
    for (int dt = 0; dt < 4; ++dt)
#pragma unroll
      for (int r = 0; r < 4; ++r) {
        const int row = qB + (rb * 16 + kg * 4 + r) * 4 + w;
        const float inv = 1.0f / s[rb][r];
        Y[((size_t)b * 2048 + row) * 1024 + h * 64 + dt * 16 + rh] = f2bf(yacc[rb][dt][r] * inv);
      }
}

extern "C" void kernel_launch(void* const* d_in, const int* in_sizes, int n_in,
                              void* d_out, int out_size, void* d_ws, size_t ws_size,
                              hipStream_t stream) {
  const float* x      = (const float*)d_in[0];  // [4,2048,1024] fp32
  const float* w_qkv  = (const float*)d_in[1];  // [1024,3072]   fp32
  const float* w_proj = (const float*)d_in[2];  // [1024,1024]   fp32
  const float* b_proj = (const float*)d_in[3];  // [1024]        fp32
  float* out = (float*)d_out;                   // [4,2048,1024] fp32

  char* ws = (char*)d_ws;
  u16* wqkvT  = (u16*)(ws);             // [3072][1024] bf16  6.29 MB
  u16* wprojT = (u16*)(ws + 6291456);   // [1024][1024] bf16  2.10 MB
  u16* Qb     = (u16*)(ws + 8388608);   // [64][2048][64]    16.78 MB
  u16* Kb     = (u16*)(ws + 25165824);  // [64][2048][64]    16.78 MB
  u16* VTb    = (u16*)(ws + 41943040);  // [64][64][2048]    16.78 MB
  u16* Yb     = (u16*)(ws + 58720256);  // [8192][1024]      16.78 MB (total 75.5 MB)

  k_transpose<<<dim3(48, 16), 256, 0, stream>>>(w_qkv, wqkvT, 1024, 3072);
  k_transpose<<<dim3(16, 16), 256, 0, stream>>>(w_proj, wprojT, 1024, 1024);
  k_gemm<1><<<dim3(24, 64), 256, 0, stream>>>(x, wqkvT, nullptr, nullptr,
                                              Qb, Kb, VTb, 8192, 3072, 1024);
  k_attn<<<dim3(64, 16), 256, 0, stream>>>(Qb, Kb, VTb, Yb);
  k_gemm<0><<<dim3(8, 64), 256, 0, stream>>>(Yb, wprojT, b_proj, out,
                                             nullptr, nullptr, nullptr, 8192, 1024, 1024);
}

// Round 9
// 258.938 us; speedup vs baseline: 1.7686x; 1.7686x over previous
//
#include <hip/hip_runtime.h>

typedef unsigned short u16;
typedef unsigned int u32;
typedef __attribute__((ext_vector_type(8))) short bf16x8;
typedef __attribute__((ext_vector_type(4))) float f32x4;
typedef __attribute__((ext_vector_type(16))) float f32x16;
typedef __attribute__((ext_vector_type(4))) unsigned short u16x4;

#define MFMA16(a, b, c) __builtin_amdgcn_mfma_f32_16x16x32_bf16((a), (b), (c), 0, 0, 0)
#define MFMA32(a, b, c) __builtin_amdgcn_mfma_f32_32x32x16_bf16((a), (b), (c), 0, 0, 0)

__device__ __forceinline__ u16 f2bf(float f) {
  union { float f; unsigned int i; } v; v.f = f;
  return (u16)((v.i + 0x7FFFu + ((v.i >> 16) & 1u)) >> 16);
}
__device__ __forceinline__ u32 pack2(float a, float b) {
  return (u32)f2bf(a) | ((u32)f2bf(b) << 16);
}

// ---------------- transpose fp32 -> bf16: dst[C][R] = src[R][C] ----------------
__global__ __launch_bounds__(256) void k_transpose(const float* __restrict__ src,
                                                   u16* __restrict__ dst, int R, int C) {
  __shared__ u16 tile[64][65];
  const int c0 = blockIdx.x * 64, r0 = blockIdx.y * 64;
  const int t = threadIdx.x;
#pragma unroll
  for (int i = 0; i < 16; ++i) {
    int e = i * 256 + t, rr = e >> 6, cc = e & 63;
    tile[rr][cc] = f2bf(src[(size_t)(r0 + rr) * C + c0 + cc]);
  }
  __syncthreads();
#pragma unroll
  for (int i = 0; i < 16; ++i) {
    int e = i * 256 + t, rr = e >> 6, cc = e & 63;
    dst[(size_t)(c0 + rr) * R + r0 + cc] = tile[cc][rr];
  }
}

// ---------------- GEMM: A[M][K] @ Bt[N][K]^T ----------------
// QKV=1: A fp32, epilogue scatters bf16 to Q/K/V^T.
// QKV=0: A bf16, epilogue writes fp32 C + fp32 bias.
template <int QKV>
__global__ __launch_bounds__(256) void k_gemm(
    const void* __restrict__ Ap, const u16* __restrict__ Bt,
    const float* __restrict__ bias, float* __restrict__ Cf,
    u16* __restrict__ Qb, u16* __restrict__ Kb, u16* __restrict__ VTb,
    int M, int N, int K) {
  __shared__ __attribute__((aligned(16))) u16 As[128 * 32];  // [row][k]
  __shared__ __attribute__((aligned(16))) u16 Bs[128 * 32];  // [col][k]
  const int bn = blockIdx.x, bm = blockIdx.y;
  const int t = threadIdx.x, lane = t & 63, w = t >> 6;
  const int wr = w >> 1, wc = w & 1;        // 2x2 wave grid, 64x64 per wave
  const int rh = lane & 15, kg = lane >> 4; // fragment row / k-group

  f32x4 acc[4][4];
#pragma unroll
  for (int mi = 0; mi < 4; ++mi)
#pragma unroll
    for (int ni = 0; ni < 4; ++ni) acc[mi][ni] = (f32x4)0.0f;

  for (int k0 = 0; k0 < K; k0 += 32) {
#pragma unroll
    for (int i = 0; i < 2; ++i) {
      int c = t + 256 * i;
      int r = c >> 2, c8 = (c & 3) << 3;
      // A tile
      if (QKV) {  // fp32 -> bf16
        const float* s = (const float*)Ap + (size_t)(bm * 128 + r) * K + k0 + c8;
        float4 a = *(const float4*)s;
        float4 b4 = *(const float4*)(s + 4);
        union { u16 e[8]; int4 v; } u;
        u.e[0] = f2bf(a.x); u.e[1] = f2bf(a.y); u.e[2] = f2bf(a.z); u.e[3] = f2bf(a.w);
        u.e[4] = f2bf(b4.x); u.e[5] = f2bf(b4.y); u.e[6] = f2bf(b4.z); u.e[7] = f2bf(b4.w);
        *(int4*)(&As[r * 32 + c8]) = u.v;
      } else {    // bf16 copy
        const u16* s = (const u16*)Ap + (size_t)(bm * 128 + r) * K + k0 + c8;
        *(int4*)(&As[r * 32 + c8]) = *(const int4*)s;
      }
      // B tile: bf16 [N][K] -> contiguous 16B copy (conflict-free)
      const u16* sb = Bt + (size_t)(bn * 128 + r) * K + k0 + c8;
      *(int4*)(&Bs[r * 32 + c8]) = *(const int4*)sb;
    }
    __syncthreads();
    bf16x8 af[4], bfr[4];
#pragma unroll
    for (int mi = 0; mi < 4; ++mi)
      af[mi] = *(const bf16x8*)(&As[(wr * 64 + mi * 16 + rh) * 32 + kg * 8]);
#pragma unroll
    for (int ni = 0; ni < 4; ++ni)
      bfr[ni] = *(const bf16x8*)(&Bs[(wc * 64 + ni * 16 + rh) * 32 + kg * 8]);
#pragma unroll
    for (int mi = 0; mi < 4; ++mi)
#pragma unroll
      for (int ni = 0; ni < 4; ++ni)
        acc[mi][ni] = MFMA16(af[mi], bfr[ni], acc[mi][ni]);
    __syncthreads();
  }

  if (QKV == 0) {
    const int rbase = bm * 128 + wr * 64;
    const int cbase = bn * 128 + wc * 64;
#pragma unroll
    for (int ni = 0; ni < 4; ++ni) {
      const int col = cbase + ni * 16 + rh;
      const float bv = bias ? bias[col] : 0.0f;
#pragma unroll
      for (int mi = 0; mi < 4; ++mi) {
#pragma unroll
        for (int r = 0; r < 4; ++r) {
          int row = rbase + mi * 16 + kg * 4 + r;
          Cf[(size_t)row * N + col] = acc[mi][ni][r] + bv;
        }
      }
    }
  } else {
    // qkv scatter: row = b*2048+t, col in [0,3072): role=col/1024, h=(col%1024)/64, d=col%64
    const int rowbase = bm * 128 + wr * 64;
    const int b = rowbase >> 11;
    const int tb = rowbase & 2047;
    const int cbase = bn * 128 + wc * 64;  // 64-aligned -> role/h uniform per wave
    const int role = cbase >> 10;
    const int h = (cbase & 1023) >> 6;
    const int bh = b * 16 + h;
#pragma unroll
    for (int ni = 0; ni < 4; ++ni) {
      const int d = ni * 16 + rh;
#pragma unroll
      for (int mi = 0; mi < 4; ++mi) {
        const int tt = tb + mi * 16 + kg * 4;
        if (role == 2) {
          u16x4 pk;
#pragma unroll
          for (int r = 0; r < 4; ++r) pk[r] = f2bf(acc[mi][ni][r]);
          *(u16x4*)(&VTb[((size_t)bh * 64 + d) * 2048 + tt]) = pk;  // V^T[bh][d][t]
        } else {
          u16* dst = (role == 0) ? Qb : Kb;
#pragma unroll
          for (int r = 0; r < 4; ++r)
            dst[((size_t)bh * 2048 + tt + r) * 64 + d] = f2bf(acc[mi][ni][r]);
        }
      }
    }
  }
}

// ---------------- causal flash attention: swapped QK^T, in-register softmax ----------------
// Q,K: [BH][2048][64]; VT: [BH][64][2048]; Y: [B*2048][1024] bf16
// 1 wave per block; wave owns 32 q-rows. S^T = mfma32(K, Q): lane holds 16 scores of
// q-row (lane&31); partner lane (^32) holds the other 16. Row-reduce = in-lane tree +
// one shfl_xor(32). P packed to bf16 in-register, one 8-dword partner swap + cndmask
// builds PV B-frags. O^T = mfma32(V^T, P^T). No LDS, no barriers.
__global__ __launch_bounds__(64, 4) void k_attn(const u16* __restrict__ Qb,
                                                const u16* __restrict__ Kb,
                                                const u16* __restrict__ VTb,
                                                u16* __restrict__ Y) {
  const int bh = blockIdx.x;
  const int qb = 63 - (int)blockIdx.y;  // LPT: biggest q-blocks dispatch first
  const int lane = threadIdx.x & 63;
  const int q31 = lane & 31, hi = lane >> 5;
  const int q0 = qb * 32;
  const u16* Qh = Qb + (size_t)bh * 2048 * 64;
  const u16* Kh = Kb + (size_t)bh * 2048 * 64;
  const u16* Vh = VTb + (size_t)bh * 64 * 2048;
  const int b = bh >> 4, h = bh & 15;
  const float SC = 0.125f * 1.44269504f;  // qk-scale * log2(e)

  // Q B-frags: Q[q0+q31][dblk*16 + hi*8 + 0..7]
  bf16x8 qf[4];
#pragma unroll
  for (int dblk = 0; dblk < 4; ++dblk)
    qf[dblk] = *(const bf16x8*)(&Qh[(size_t)(q0 + q31) * 64 + dblk * 16 + hi * 8]);

  f32x16 o0 = (f32x16)0.0f, o1 = (f32x16)0.0f;  // O^T accum, d-blocks [0,32) and [32,64)
  float m = -1e30f, s = 0.0f;

  const int nt = qb + 1;
  for (int tt = 0; tt < nt; ++tt) {
    const int j0 = tt * 32;
    // ---- K A-frags: K[j0+q31][dblk*16 + hi*8 + ..] ----
    bf16x8 kf[4];
#pragma unroll
    for (int dblk = 0; dblk < 4; ++dblk)
      kf[dblk] = *(const bf16x8*)(&Kh[(size_t)(j0 + q31) * 64 + dblk * 16 + hi * 8]);
    // ---- S^T = K @ Q^T ----
    f32x16 st = (f32x16)0.0f;
    __builtin_amdgcn_s_setprio(1);
#pragma unroll
    for (int dblk = 0; dblk < 4; ++dblk) st = MFMA32(kf[dblk], qf[dblk], st);
    __builtin_amdgcn_s_setprio(0);

    // ---- V^T A-frags (issued early; consumed after softmax) ----
    bf16x8 v00 = *(const bf16x8*)(&Vh[(size_t)q31 * 2048 + j0 + hi * 8]);
    bf16x8 v01 = *(const bf16x8*)(&Vh[(size_t)q31 * 2048 + j0 + 16 + hi * 8]);
    bf16x8 v10 = *(const bf16x8*)(&Vh[(size_t)(32 + q31) * 2048 + j0 + hi * 8]);
    bf16x8 v11 = *(const bf16x8*)(&Vh[(size_t)(32 + q31) * 2048 + j0 + 16 + hi * 8]);

    // ---- in-register softmax (per-lane row = q0+q31) ----
    float v[16];
#pragma unroll
    for (int r = 0; r < 16; ++r) v[r] = st[r] * SC;
    if (tt == nt - 1) {  // only the diagonal tile masks (j0 == q0)
#pragma unroll
      for (int r = 0; r < 16; ++r) {
        const int kcol = (r & 3) + 8 * (r >> 2) + 4 * hi;
        if (kcol > q31) v[r] = -1e30f;
      }
    }
    float mx01 = fmaxf(fmaxf(v[0], v[1]), fmaxf(v[2], v[3]));
    float mx23 = fmaxf(fmaxf(v[4], v[5]), fmaxf(v[6], v[7]));
    float mx45 = fmaxf(fmaxf(v[8], v[9]), fmaxf(v[10], v[11]));
    float mx67 = fmaxf(fmaxf(v[12], v[13]), fmaxf(v[14], v[15]));
    float mx = fmaxf(fmaxf(mx01, mx23), fmaxf(mx45, mx67));
    mx = fmaxf(mx, __shfl_xor(mx, 32));
    const float mn = fmaxf(m, mx);
    const float scf = exp2f(m - mn);
    m = mn;
    float p[16];
    float rs = 0.0f;
#pragma unroll
    for (int r = 0; r < 16; ++r) { p[r] = exp2f(v[r] - mn); rs += p[r]; }
    rs += __shfl_xor(rs, 32);
    s = s * scf + rs;
    o0 *= scf;
    o1 *= scf;

    // ---- pack P to bf16 dwords, partner-swap, assemble PV B-frags ----
    u32 D0 = pack2(p[0], p[1]),   D1 = pack2(p[2], p[3]);
    u32 D2 = pack2(p[4], p[5]),   D3 = pack2(p[6], p[7]);
    u32 D4 = pack2(p[8], p[9]),   D5 = pack2(p[10], p[11]);
    u32 D6 = pack2(p[12], p[13]), D7 = pack2(p[14], p[15]);
    u32 X0 = __shfl_xor(D0, 32), X1 = __shfl_xor(D1, 32);
    u32 X2 = __shfl_xor(D2, 32), X3 = __shfl_xor(D3, 32);
    u32 X4 = __shfl_xor(D4, 32), X5 = __shfl_xor(D5, 32);
    u32 X6 = __shfl_xor(D6, 32), X7 = __shfl_xor(D7, 32);
    union { u32 w[4]; bf16x8 f; } pa0, pa1;
    pa0.w[0] = hi ? X2 : D0; pa0.w[1] = hi ? X3 : D1;
    pa0.w[2] = hi ? D2 : X0; pa0.w[3] = hi ? D3 : X1;
    pa1.w[0] = hi ? X6 : D4; pa1.w[1] = hi ? X7 : D5;
    pa1.w[2] = hi ? D6 : X4; pa1.w[3] = hi ? D7 : X5;

    // ---- O^T += V^T @ P^T ----
    __builtin_amdgcn_s_setprio(1);
    o0 = MFMA32(v00, pa0.f, o0);
    o0 = MFMA32(v01, pa1.f, o0);
    o1 = MFMA32(v10, pa0.f, o1);
    o1 = MFMA32(v11, pa1.f, o1);
    __builtin_amdgcn_s_setprio(0);
  }

  // ---- epilogue: Y[q0+q31][h*64 + d], d = dblk*32 + 8a + 4hi + 0..3 ----
  const float inv = 1.0f / s;
  u16* yrow = Y + ((size_t)b * 2048 + q0 + q31) * 1024 + h * 64;
#pragma unroll
  for (int a = 0; a < 4; ++a) {
    u16x4 pk;
#pragma unroll
    for (int i = 0; i < 4; ++i) pk[i] = f2bf(o0[a * 4 + i] * inv);
    *(u16x4*)(yrow + a * 8 + 4 * hi) = pk;
  }
#pragma unroll
  for (int a = 0; a < 4; ++a) {
    u16x4 pk;
#pragma unroll
    for (int i = 0; i < 4; ++i) pk[i] = f2bf(o1[a * 4 + i] * inv);
    *(u16x4*)(yrow + 32 + a * 8 + 4 * hi) = pk;
  }
}

extern "C" void kernel_launch(void* const* d_in, const int* in_sizes, int n_in,
                              void* d_out, int out_size, void* d_ws, size_t ws_size,
                              hipStream_t stream) {
  const float* x      = (const float*)d_in[0];  // [4,2048,1024] fp32
  const float* w_qkv  = (const float*)d_in[1];  // [1024,3072]   fp32
  const float* w_proj = (const float*)d_in[2];  // [1024,1024]   fp32
  const float* b_proj = (const float*)d_in[3];  // [1024]        fp32
  float* out = (float*)d_out;                   // [4,2048,1024] fp32

  char* ws = (char*)d_ws;
  u16* wqkvT  = (u16*)(ws);             // [3072][1024] bf16  6.29 MB
  u16* wprojT = (u16*)(ws + 6291456);   // [1024][1024] bf16  2.10 MB
  u16* Qb     = (u16*)(ws + 8388608);   // [64][2048][64]    16.78 MB
  u16* Kb     = (u16*)(ws + 25165824);  // [64][2048][64]    16.78 MB
  u16* VTb    = (u16*)(ws + 41943040);  // [64][64][2048]    16.78 MB
  u16* Yb     = (u16*)(ws + 58720256);  // [8192][1024]      16.78 MB (total 75.5 MB)

  k_transpose<<<dim3(48, 16), 256, 0, stream>>>(w_qkv, wqkvT, 1024, 3072);
  k_transpose<<<dim3(16, 16), 256, 0, stream>>>(w_proj, wprojT, 1024, 1024);
  k_gemm<1><<<dim3(24, 64), 256, 0, stream>>>(x, wqkvT, nullptr, nullptr,
                                              Qb, Kb, VTb, 8192, 3072, 1024);
  k_attn<<<dim3(64, 64), 64, 0, stream>>>(Qb, Kb, VTb, (u16*)Yb);
  k_gemm<0><<<dim3(8, 64), 256, 0, stream>>>(Yb, wprojT, b_proj, out,
                                             nullptr, nullptr, nullptr, 8192, 1024, 1024);
}

// Round 11
// 255.618 us; speedup vs baseline: 1.7916x; 1.0130x over previous
//
#include <hip/hip_runtime.h>

typedef unsigned short u16;
typedef unsigned int u32;
typedef __attribute__((ext_vector_type(8))) short bf16x8;
typedef __attribute__((ext_vector_type(4))) float f32x4;
typedef __attribute__((ext_vector_type(16))) float f32x16;
typedef __attribute__((ext_vector_type(4))) unsigned short u16x4;

#define MFMA16(a, b, c) __builtin_amdgcn_mfma_f32_16x16x32_bf16((a), (b), (c), 0, 0, 0)
#define MFMA32(a, b, c) __builtin_amdgcn_mfma_f32_32x32x16_bf16((a), (b), (c), 0, 0, 0)

__device__ __forceinline__ u16 f2bf(float f) {
  union { float f; unsigned int i; } v; v.f = f;
  return (u16)((v.i + 0x7FFFu + ((v.i >> 16) & 1u)) >> 16);
}
__device__ __forceinline__ float exp2a(float x) {  // raw v_exp_f32 (2^x)
  float r; asm("v_exp_f32 %0, %1" : "=v"(r) : "v"(x)); return r;
}
__device__ __forceinline__ u32 cvtpk(float lo, float hi) {  // [bf16(lo) | bf16(hi)<<16]
  u32 d; asm("v_cvt_pk_bf16_f32 %0, %1, %2" : "=v"(d) : "v"(lo), "v"(hi)); return d;
}

// ---------------- transpose fp32 -> bf16: dst[C][R] = src[R][C] ----------------
__global__ __launch_bounds__(256) void k_transpose(const float* __restrict__ src,
                                                   u16* __restrict__ dst, int R, int C) {
  __shared__ u16 tile[64][65];
  const int c0 = blockIdx.x * 64, r0 = blockIdx.y * 64;
  const int t = threadIdx.x;
#pragma unroll
  for (int i = 0; i < 16; ++i) {
    int e = i * 256 + t, rr = e >> 6, cc = e & 63;
    tile[rr][cc] = f2bf(src[(size_t)(r0 + rr) * C + c0 + cc]);
  }
  __syncthreads();
#pragma unroll
  for (int i = 0; i < 16; ++i) {
    int e = i * 256 + t, rr = e >> 6, cc = e & 63;
    dst[(size_t)(c0 + rr) * R + r0 + cc] = tile[cc][rr];
  }
}

// ---------------- GEMM: A[M][K] @ Bt[N][K]^T ----------------
// QKV=1: A fp32, epilogue scatters bf16 to Q/K/V^T (Q pre-scaled by 1/sqrt(d)*log2e).
// QKV=0: A bf16, epilogue writes fp32 C + fp32 bias.
template <int QKV>
__global__ __launch_bounds__(256) void k_gemm(
    const void* __restrict__ Ap, const u16* __restrict__ Bt,
    const float* __restrict__ bias, float* __restrict__ Cf,
    u16* __restrict__ Qb, u16* __restrict__ Kb, u16* __restrict__ VTb,
    int M, int N, int K) {
  __shared__ __attribute__((aligned(16))) u16 As[128 * 32];  // [row][k]
  __shared__ __attribute__((aligned(16))) u16 Bs[128 * 32];  // [col][k]
  const int bn = blockIdx.x, bm = blockIdx.y;
  const int t = threadIdx.x, lane = t & 63, w = t >> 6;
  const int wr = w >> 1, wc = w & 1;        // 2x2 wave grid, 64x64 per wave
  const int rh = lane & 15, kg = lane >> 4; // fragment row / k-group

  f32x4 acc[4][4];
#pragma unroll
  for (int mi = 0; mi < 4; ++mi)
#pragma unroll
    for (int ni = 0; ni < 4; ++ni) acc[mi][ni] = (f32x4)0.0f;

  for (int k0 = 0; k0 < K; k0 += 32) {
#pragma unroll
    for (int i = 0; i < 2; ++i) {
      int c = t + 256 * i;
      int r = c >> 2, c8 = (c & 3) << 3;
      // A tile
      if (QKV) {  // fp32 -> bf16
        const float* s = (const float*)Ap + (size_t)(bm * 128 + r) * K + k0 + c8;
        float4 a = *(const float4*)s;
        float4 b4 = *(const float4*)(s + 4);
        union { u16 e[8]; int4 v; } u;
        u.e[0] = f2bf(a.x); u.e[1] = f2bf(a.y); u.e[2] = f2bf(a.z); u.e[3] = f2bf(a.w);
        u.e[4] = f2bf(b4.x); u.e[5] = f2bf(b4.y); u.e[6] = f2bf(b4.z); u.e[7] = f2bf(b4.w);
        *(int4*)(&As[r * 32 + c8]) = u.v;
      } else {    // bf16 copy
        const u16* s = (const u16*)Ap + (size_t)(bm * 128 + r) * K + k0 + c8;
        *(int4*)(&As[r * 32 + c8]) = *(const int4*)s;
      }
      // B tile: bf16 [N][K] -> contiguous 16B copy (conflict-free)
      const u16* sb = Bt + (size_t)(bn * 128 + r) * K + k0 + c8;
      *(int4*)(&Bs[r * 32 + c8]) = *(const int4*)sb;
    }
    __syncthreads();
    bf16x8 af[4], bfr[4];
#pragma unroll
    for (int mi = 0; mi < 4; ++mi)
      af[mi] = *(const bf16x8*)(&As[(wr * 64 + mi * 16 + rh) * 32 + kg * 8]);
#pragma unroll
    for (int ni = 0; ni < 4; ++ni)
      bfr[ni] = *(const bf16x8*)(&Bs[(wc * 64 + ni * 16 + rh) * 32 + kg * 8]);
#pragma unroll
    for (int mi = 0; mi < 4; ++mi)
#pragma unroll
      for (int ni = 0; ni < 4; ++ni)
        acc[mi][ni] = MFMA16(af[mi], bfr[ni], acc[mi][ni]);
    __syncthreads();
  }

  if (QKV == 0) {
    const int rbase = bm * 128 + wr * 64;
    const int cbase = bn * 128 + wc * 64;
#pragma unroll
    for (int ni = 0; ni < 4; ++ni) {
      const int col = cbase + ni * 16 + rh;
      const float bv = bias ? bias[col] : 0.0f;
#pragma unroll
      for (int mi = 0; mi < 4; ++mi) {
#pragma unroll
        for (int r = 0; r < 4; ++r) {
          int row = rbase + mi * 16 + kg * 4 + r;
          Cf[(size_t)row * N + col] = acc[mi][ni][r] + bv;
        }
      }
    }
  } else {
    // qkv scatter: row = b*2048+t, col in [0,3072): role=col/1024, h=(col%1024)/64, d=col%64
    const float SCQ = 0.125f * 1.44269504f;  // qk-scale * log2(e), folded into Q
    const int rowbase = bm * 128 + wr * 64;
    const int b = rowbase >> 11;
    const int tb = rowbase & 2047;
    const int cbase = bn * 128 + wc * 64;  // 64-aligned -> role/h uniform per wave
    const int role = cbase >> 10;
    const int h = (cbase & 1023) >> 6;
    const int bh = b * 16 + h;
#pragma unroll
    for (int ni = 0; ni < 4; ++ni) {
      const int d = ni * 16 + rh;
#pragma unroll
      for (int mi = 0; mi < 4; ++mi) {
        const int tt = tb + mi * 16 + kg * 4;
        if (role == 2) {
          u16x4 pk;
#pragma unroll
          for (int r = 0; r < 4; ++r) pk[r] = f2bf(acc[mi][ni][r]);
          *(u16x4*)(&VTb[((size_t)bh * 64 + d) * 2048 + tt]) = pk;  // V^T[bh][d][t]
        } else {
          u16* dst = (role == 0) ? Qb : Kb;
          const float sc = (role == 0) ? SCQ : 1.0f;
#pragma unroll
          for (int r = 0; r < 4; ++r)
            dst[((size_t)bh * 2048 + tt + r) * 64 + d] = f2bf(acc[mi][ni][r] * sc);
        }
      }
    }
  }
}

// ---------------- causal flash attention: swapped QK^T, in-register softmax ----------------
// Q,K: [BH][2048][64]; VT: [BH][64][2048]; Y: [B*2048][1024] bf16
// Block = 128 thr = 2 independent waves handling qb = y and 63-y (65 tiles/block
// uniform -> perfect balance). S^T = mfma32(K, Q); cross-lane via __shfl_xor(·,32)
// (round-9-proven); P packed via v_cvt_pk_bf16_f32; defer-max THR=8 (log2 domain).
__global__ __launch_bounds__(128, 4) void k_attn(const u16* __restrict__ Qb,
                                                 const u16* __restrict__ Kb,
                                                 const u16* __restrict__ VTb,
                                                 u16* __restrict__ Y) {
  const int bh = blockIdx.x;
  const int w = threadIdx.x >> 6;
  const int qb = w ? 63 - (int)blockIdx.y : (int)blockIdx.y;
  const int lane = threadIdx.x & 63;
  const int q31 = lane & 31, hi = lane >> 5;
  const int q0 = qb * 32;
  const u16* Qh = Qb + (size_t)bh * 2048 * 64;
  const u16* Kh = Kb + (size_t)bh * 2048 * 64;
  const u16* Vh = VTb + (size_t)bh * 64 * 2048;
  const int b = bh >> 4, h = bh & 15;

  // Q B-frags: Q[q0+q31][dblk*16 + hi*8 + 0..7] (pre-scaled by SCQ in GEMM1)
  bf16x8 qf[4];
#pragma unroll
  for (int dblk = 0; dblk < 4; ++dblk)
    qf[dblk] = *(const bf16x8*)(&Qh[(size_t)(q0 + q31) * 64 + dblk * 16 + hi * 8]);

  f32x16 o0 = (f32x16)0.0f, o1 = (f32x16)0.0f;  // O^T accum, d-blocks [0,32) and [32,64)
  float m = -1e30f, s = 0.0f;

  const int nt = qb + 1;
  for (int tt = 0; tt < nt; ++tt) {
    const int j0 = tt * 32;
    // ---- K A-frags ----
    bf16x8 kf[4];
#pragma unroll
    for (int dblk = 0; dblk < 4; ++dblk)
      kf[dblk] = *(const bf16x8*)(&Kh[(size_t)(j0 + q31) * 64 + dblk * 16 + hi * 8]);
    // ---- S^T = K @ Q^T (scores in log2 domain via pre-scaled Q) ----
    f32x16 st = (f32x16)0.0f;
    __builtin_amdgcn_s_setprio(1);
#pragma unroll
    for (int dblk = 0; dblk < 4; ++dblk) st = MFMA32(kf[dblk], qf[dblk], st);
    __builtin_amdgcn_s_setprio(0);

    // ---- V^T A-frags (issued early; consumed after softmax) ----
    bf16x8 v00 = *(const bf16x8*)(&Vh[(size_t)q31 * 2048 + j0 + hi * 8]);
    bf16x8 v01 = *(const bf16x8*)(&Vh[(size_t)q31 * 2048 + j0 + 16 + hi * 8]);
    bf16x8 v10 = *(const bf16x8*)(&Vh[(size_t)(32 + q31) * 2048 + j0 + hi * 8]);
    bf16x8 v11 = *(const bf16x8*)(&Vh[(size_t)(32 + q31) * 2048 + j0 + 16 + hi * 8]);

    // ---- mask (diagonal tile only) ----
    if (tt == nt - 1) {
#pragma unroll
      for (int r = 0; r < 16; ++r) {
        const int kcol = (r & 3) + 8 * (r >> 2) + 4 * hi;
        if (kcol > q31) st[r] = -1e30f;
      }
    }

    // ---- in-register softmax with defer-max (THR=8 in log2 domain) ----
    float mx = fmaxf(
        fmaxf(fmaxf(fmaxf(st[0], st[1]), fmaxf(st[2], st[3])),
              fmaxf(fmaxf(st[4], st[5]), fmaxf(st[6], st[7]))),
        fmaxf(fmaxf(fmaxf(st[8], st[9]), fmaxf(st[10], st[11])),
              fmaxf(fmaxf(st[12], st[13]), fmaxf(st[14], st[15]))));
    mx = fmaxf(mx, __shfl_xor(mx, 32));
    if (__any(mx - m > 8.0f)) {  // wave-collective rescale (rare after warmup)
      const float mn = fmaxf(m, mx);
      const float scf = exp2a(m - mn);
      m = mn;
      s *= scf;
      o0 *= scf;
      o1 *= scf;
    }
    float p[16];
#pragma unroll
    for (int r = 0; r < 16; ++r) p[r] = exp2a(st[r] - m);
    float rs = (((p[0] + p[1]) + (p[2] + p[3])) + ((p[4] + p[5]) + (p[6] + p[7]))) +
               (((p[8] + p[9]) + (p[10] + p[11])) + ((p[12] + p[13]) + (p[14] + p[15])));
    rs += __shfl_xor(rs, 32);
    s += rs;

    // ---- pack P -> bf16 dwords, partner-swap via shfl, assemble PV B-frags ----
    u32 D0 = cvtpk(p[0], p[1]),   D1 = cvtpk(p[2], p[3]);
    u32 D2 = cvtpk(p[4], p[5]),   D3 = cvtpk(p[6], p[7]);
    u32 D4 = cvtpk(p[8], p[9]),   D5 = cvtpk(p[10], p[11]);
    u32 D6 = cvtpk(p[12], p[13]), D7 = cvtpk(p[14], p[15]);
    u32 X0 = __shfl_xor(D0, 32), X1 = __shfl_xor(D1, 32);
    u32 X2 = __shfl_xor(D2, 32), X3 = __shfl_xor(D3, 32);
    u32 X4 = __shfl_xor(D4, 32), X5 = __shfl_xor(D5, 32);
    u32 X6 = __shfl_xor(D6, 32), X7 = __shfl_xor(D7, 32);
    union { u32 w[4]; bf16x8 f; } pa0, pa1;
    pa0.w[0] = hi ? X2 : D0; pa0.w[1] = hi ? X3 : D1;
    pa0.w[2] = hi ? D2 : X0; pa0.w[3] = hi ? D3 : X1;
    pa1.w[0] = hi ? X6 : D4; pa1.w[1] = hi ? X7 : D5;
    pa1.w[2] = hi ? D6 : X4; pa1.w[3] = hi ? D7 : X5;

    // ---- O^T += V^T @ P^T ----
    __builtin_amdgcn_s_setprio(1);
    o0 = MFMA32(v00, pa0.f, o0);
    o0 = MFMA32(v01, pa1.f, o0);
    o1 = MFMA32(v10, pa0.f, o1);
    o1 = MFMA32(v11, pa1.f, o1);
    __builtin_amdgcn_s_setprio(0);
  }

  // ---- epilogue: Y[q0+q31][h*64 + d], d = dblk*32 + 8a + 4hi + 0..3 ----
  const float inv = 1.0f / s;
  u16* yrow = Y + ((size_t)b * 2048 + q0 + q31) * 1024 + h * 64;
#pragma unroll
  for (int a = 0; a < 4; ++a) {
    u16x4 pk;
#pragma unroll
    for (int i = 0; i < 4; ++i) pk[i] = f2bf(o0[a * 4 + i] * inv);
    *(u16x4*)(yrow + a * 8 + 4 * hi) = pk;
  }
#pragma unroll
  for (int a = 0; a < 4; ++a) {
    u16x4 pk;
#pragma unroll
    for (int i = 0; i < 4; ++i) pk[i] = f2bf(o1[a * 4 + i] * inv);
    *(u16x4*)(yrow + 32 + a * 8 + 4 * hi) = pk;
  }
}

extern "C" void kernel_launch(void* const* d_in, const int* in_sizes, int n_in,
                              void* d_out, int out_size, void* d_ws, size_t ws_size,
                              hipStream_t stream) {
  const float* x      = (const float*)d_in[0];  // [4,2048,1024] fp32
  const float* w_qkv  = (const float*)d_in[1];  // [1024,3072]   fp32
  const float* w_proj = (const float*)d_in[2];  // [1024,1024]   fp32
  const float* b_proj = (const float*)d_in[3];  // [1024]        fp32
  float* out = (float*)d_out;                   // [4,2048,1024] fp32

  char* ws = (char*)d_ws;
  u16* wqkvT  = (u16*)(ws);             // [3072][1024] bf16  6.29 MB
  u16* wprojT = (u16*)(ws + 6291456);   // [1024][1024] bf16  2.10 MB
  u16* Qb     = (u16*)(ws + 8388608);   // [64][2048][64]    16.78 MB
  u16* Kb     = (u16*)(ws + 25165824);  // [64][2048][64]    16.78 MB
  u16* VTb    = (u16*)(ws + 41943040);  // [64][64][2048]    16.78 MB
  u16* Yb     = (u16*)(ws + 58720256);  // [8192][1024]      16.78 MB (total 75.5 MB)

  k_transpose<<<dim3(48, 16), 256, 0, stream>>>(w_qkv, wqkvT, 1024, 3072);
  k_transpose<<<dim3(16, 16), 256, 0, stream>>>(w_proj, wprojT, 1024, 1024);
  k_gemm<1><<<dim3(24, 64), 256, 0, stream>>>(x, wqkvT, nullptr, nullptr,
                                              Qb, Kb, VTb, 8192, 3072, 1024);
  k_attn<<<dim3(64, 32), 128, 0, stream>>>(Qb, Kb, VTb, (u16*)Yb);
  k_gemm<0><<<dim3(8, 64), 256, 0, stream>>>(Yb, wprojT, b_proj, out,
                                             nullptr, nullptr, nullptr, 8192, 1024, 1024);
}